// Round 9
// baseline (1392.314 us; speedup 1.0000x reference)
//
#include <hip/hip_runtime.h>
#include <math.h>

typedef unsigned short u16;
typedef __attribute__((ext_vector_type(8))) short bf16x8;
typedef __attribute__((ext_vector_type(4))) float f32x4;

#define PSUB8 540800   // elems per padded 8-ch sub-plane: 4*130*130*8
#define TSUB8 524288   // elems per compact 8-ch sub-plane: 4*128*128*8

__device__ __forceinline__ u16 f2bf(float f) {
  unsigned u = __float_as_uint(f);
  unsigned r = u + 0x7fffu + ((u >> 16) & 1u);
  return (u16)(r >> 16);
}
__device__ __forceinline__ float bf2f(u16 h) {
  return __uint_as_float(((unsigned)h) << 16);
}
__device__ __forceinline__ void gl16(const u16* g, const u16* l) {
  __builtin_amdgcn_global_load_lds(
      (const __attribute__((address_space(1))) void*)g,
      (__attribute__((address_space(3))) void*)l, 16, 0, 0);
}

// ---------- quantize + s2d into padded bf16 8-ch group planes ---------------
__global__ void quant_s2d_kernel(const float* __restrict__ inp,
                                 float* __restrict__ q,
                                 u16* __restrict__ yghi) {
  int idx = blockIdx.x * 256 + threadIdx.x;   // 33,554,432
  int ww = idx & 255;
  int hh = (idx >> 8) & 255;
  int cc = (idx >> 16) & 127;
  int b  = idx >> 23;
  float v = rintf(inp[idx]);
  q[idx] = v;
  int g = cc >> 5;
  int f = ((cc & 31) << 2) | ((hh & 1) << 1) | (ww & 1);
  int y = hh >> 1, x = ww >> 1;
  int p = (b * 130 + y + 1) * 130 + 1 + x;
  yghi[((size_t)(g * 16 + (f >> 3))) * PSUB8 + (size_t)p * 8 + (f & 7)] = f2bf(v);
}

// ---------- s2d of condition -> h0 (8-ch planes) + c0 (compact fp32) --------
__global__ void s2d_cond_kernel(const float* __restrict__ cond,
                                u16* __restrict__ hhi, float* __restrict__ c0) {
  int idx = blockIdx.x * 256 + threadIdx.x;   // 8,388,608
  int ww = idx & 255;
  int hh = (idx >> 8) & 255;
  int cc = (idx >> 16) & 31;
  int b  = idx >> 21;
  float v = cond[idx];
  int ch = (cc << 2) | ((hh & 1) << 1) | (ww & 1);
  int y = hh >> 1, x = ww >> 1;
  int p = (b * 130 + y + 1) * 130 + 1 + x;
  hhi[(size_t)(ch >> 3) * PSUB8 + (size_t)p * 8 + (ch & 7)] = f2bf(v);
  c0[((size_t)(b * 128 + y) * 128 + x) * 128 + ch] = v;
}

// ---------- weight pack: per (cb, slab) 256-col block layout ----------------
// Wpk[(cb*NSLAB+slab)*8192 + wn*2048 + ni*512 + lane*8 + jj]
// col c = cb*256 + wn*64 + ni*16 + (lane&15); k = slab*32 + (lane>>4)*8 + jj
// PERM 0: LSTM gate perm; 1: identity; 2: w3 mean/scale perm
template <int TAPS, int PERM>
__global__ void build_wpack(const float* __restrict__ w, u16* __restrict__ o) {
  int idx = blockIdx.x * 256 + threadIdx.x;
  int jj = idx & 7, lane = (idx >> 3) & 63, ni = (idx >> 9) & 3, wn = (idx >> 11) & 3;
  int rest = idx >> 13;
  const int NSLAB = TAPS * 8;
  int slab = rest % NSLAB, cb = rest / NSLAB;
  int c = cb * 256 + wn * 64 + ni * 16 + (lane & 15);
  int k = slab * 32 + ((lane >> 4) << 3) + jj;
  int tap = (TAPS == 9) ? (k >> 8) : 0;
  int ci = (TAPS == 9) ? (k & 255) : k;
  int oc;
  if (PERM == 0)      oc = ((c >> 4) & 3) * 128 + (c >> 7) * 32 + ((c >> 6) & 1) * 16 + (c & 15);
  else if (PERM == 2) oc = ((c >> 4) & 1) * 128 + (c >> 7) * 64 + ((c >> 6) & 1) * 32 + ((c >> 5) & 1) * 16 + (c & 15);
  else                oc = c;
  float v = w[((size_t)(oc * 256 + ci)) * TAPS + tap];
  o[idx] = f2bf(v);
}

__global__ void make_biases(const float* __restrict__ lb, const float* __restrict__ b1,
                            const float* __restrict__ b2, const float* __restrict__ b3,
                            float* __restrict__ pl, float* __restrict__ p1,
                            float* __restrict__ p2, float* __restrict__ p3) {
  int t = blockIdx.x * 256 + threadIdx.x;     // launch 512
  if (t < 512) {
    int gate = (t >> 4) & 3;
    int f = (t >> 7) * 32 + ((t >> 6) & 1) * 16 + (t & 15);
    pl[t] = lb[gate * 128 + f];
  }
  if (t < 256) {
    p1[t] = b1[t];
    p2[t] = b2[t];
    int m = (t >> 4) & 1;
    int f = (t >> 7) * 64 + ((t >> 6) & 1) * 32 + ((t >> 5) & 1) * 16 + (t & 15);
    p3[t] = b3[m * 128 + f];
  }
}

// ---------- MFMA conv: 128px x 256col block, 4 waves (1x4), 8x4 acc ---------
// A in LDS k-major: [kq(4)][px(128)][8ch] per slab -> both staging (1024B/op)
// and fragment reads (16-lane phase = 256B contiguous) are conflict-free.
// W in LDS [wn(4)][ni(4)][lane(64)][8] -> conflict-free.
// Pipeline: stage(s+1) {A:2 + W:4 ops/wave} -> vmcnt(6) (stage(s) landed,
// stage(s+1) IN FLIGHT across barrier) -> s_barrier -> 32 MFMA/wave ->
// s_barrier (reuse guard). vmcnt(0) only on the last slab.
// EPI 0: LSTM update; EPI 1: lrelu -> 8-ch planes; EPI 2: likelihood.
template <int TAPS, int NCOL, int EPI>
__global__ __launch_bounds__(256, 2)
void conv_mfma(const u16* __restrict__ a0, const u16* __restrict__ a1,
               int RS, int PAD, int skiphalf,
               const u16* __restrict__ Wpk, const float* __restrict__ biasP,
               float* __restrict__ c_io,
               u16* __restrict__ ohi, size_t OSUB, int ORS, int OPAD,
               const u16* __restrict__ zsrc, float* __restrict__ lik, int g) {
  constexpr int NSLAB = TAPS * 8;
  constexpr int NCB = NCOL / 256;
  constexpr size_t PST = (TAPS == 1 && EPI == 2) ? (size_t)TSUB8 : (size_t)PSUB8;
  __shared__ __attribute__((aligned(16))) u16 lds[24576];  // A dbuf 2x4096, W dbuf 2x8192
  const int tid = threadIdx.x;
  const int lane = tid & 63, wn = tid >> 6;
  const int fl = lane & 15, kq = lane >> 4;

  // XCD swizzle: each XCD gets contiguous y-strips x all cb
  int n = blockIdx.y * NCB + blockIdx.x;
  int w_ = n >> 9, r_ = n & 511;
  int xj = r_ & 7, tt = r_ >> 3;
  const int cb = tt & (NCB - 1);
  const int YL = 64 / NCB;
  int ystrip = w_ * (8 * YL) + xj * YL + (tt / NCB);
  const int b = ystrip >> 7, y = ystrip & 127;

  const int NS = skiphalf ? NSLAB / 2 : NSLAB;
  f32x4 acc[8][4] = {};

  auto mapslab = [&](int si) -> int {
    if (!skiphalf) return si;
    int tap = si >> 2, o = si & 3;
    return tap * 8 + (skiphalf == 1 ? 4 + o : o);
  };
  auto stage = [&](int si, int buf) {   // 6 gl16 per wave (2 A + 4 W)
    int s = mapslab(si);
    int dy = 0, dx = 0;
    if (TAPS == 9) { int tap = s >> 3; dy = tap / 3 - 1; dx = tap % 3 - 1; }
    int cc = s & 7;
    const u16* base = (cc < 4) ? a0 : a1;
    int origin = (b * RS + y + PAD) * RS + PAD + dy * RS + dx;
#pragma unroll
    for (int t = 0; t < 2; ++t) {
      int j = wn * 2 + t;               // j=0..7: kq=j>>1, px-half=j&1
      const u16* src = base + (size_t)((cc & 3) * 4 + (j >> 1)) * PST
                            + (size_t)(origin + (j & 1) * 64) * 8;
      gl16(src + lane * 8, &lds[buf * 4096 + j * 512]);
    }
    const u16* wbase = Wpk + ((size_t)(cb * NSLAB + s)) * 8192;
#pragma unroll
    for (int t = 0; t < 4; ++t) {
      int j = wn * 4 + t;               // j=0..15
      gl16(wbase + j * 512 + lane * 8, &lds[8192 + buf * 8192 + j * 512]);
    }
  };
  auto compute = [&](int buf) {
    bf16x8 Wf[4];
#pragma unroll
    for (int i = 0; i < 4; ++i)
      Wf[i] = *(const bf16x8*)&lds[8192 + buf * 8192 + wn * 2048 + i * 512 + lane * 8];
    __builtin_amdgcn_s_setprio(1);
#pragma unroll
    for (int mi = 0; mi < 8; ++mi) {
      bf16x8 Ah = *(const bf16x8*)&lds[buf * 4096 + kq * 1024 + (mi * 16 + fl) * 8];
#pragma unroll
      for (int ni = 0; ni < 4; ++ni)
        acc[mi][ni] = __builtin_amdgcn_mfma_f32_16x16x32_bf16(Ah, Wf[ni], acc[mi][ni], 0, 0, 0);
    }
    __builtin_amdgcn_s_setprio(0);
  };

  stage(0, 0);
  for (int s = 0; s < NS; ++s) {
    if (s + 1 < NS) {
      stage(s + 1, (s + 1) & 1);
      asm volatile("s_waitcnt vmcnt(6)" ::: "memory");   // stage(s) landed
    } else {
      asm volatile("s_waitcnt vmcnt(0)" ::: "memory");
    }
    __builtin_amdgcn_s_barrier();       // all waves' stage(s) visible
    compute(s & 1);
    __builtin_amdgcn_s_barrier();       // reads of buf done before restage
  }

  if (EPI == 0) {
    const int f = cb * 64 + wn * 16 + fl;           // ni = gate (PERM 0)
    float bi[4];
#pragma unroll
    for (int ni = 0; ni < 4; ++ni) bi[ni] = biasP[cb * 256 + wn * 64 + ni * 16 + fl];
#pragma unroll
    for (int mi = 0; mi < 8; ++mi)
#pragma unroll
      for (int r = 0; r < 4; ++r) {
        int x = mi * 16 + kq * 4 + r;
        size_t ci = ((size_t)(b * 128 + y) * 128 + x) * 128 + f;
        float ig = 1.f / (1.f + expf(-(acc[mi][0][r] + bi[0])));
        float fg = 1.f / (1.f + expf(-(acc[mi][1][r] + bi[1])));
        float og = 1.f / (1.f + expf(-(acc[mi][2][r] + bi[2])));
        float gg = tanhf(acc[mi][3][r] + bi[3]);
        float cn = fg * c_io[ci] + ig * gg;
        c_io[ci] = cn;
        float hv = og * tanhf(cn);
        size_t hx = (size_t)((b * 130 + y + 1) * 130 + 1 + x);
        ohi[(size_t)(f >> 3) * PSUB8 + hx * 8 + (f & 7)] = f2bf(hv);
      }
  } else if (EPI == 1) {
#pragma unroll
    for (int ni = 0; ni < 4; ++ni) {
      int c = wn * 64 + ni * 16 + fl;               // NCOL==256, identity perm
      float bv = biasP[c];
#pragma unroll
      for (int mi = 0; mi < 8; ++mi)
#pragma unroll
        for (int r = 0; r < 4; ++r) {
          int x = mi * 16 + kq * 4 + r;
          float v = acc[mi][ni][r] + bv;
          v = (v >= 0.f) ? v : 0.01f * v;
          size_t op = (size_t)((b * ORS + y + OPAD) * ORS + OPAD + x);
          ohi[(size_t)(c >> 3) * OSUB + op * 8 + (c & 7)] = f2bf(v);
        }
    }
  } else {
#pragma unroll
    for (int j = 0; j < 2; ++j) {
      int f = wn * 32 + j * 16 + fl;                // PERM 2: ni=2j mean, 2j+1 scale
      float bm = biasP[wn * 64 + j * 32 + fl];
      float bs = biasP[wn * 64 + j * 32 + 16 + fl];
#pragma unroll
      for (int mi = 0; mi < 8; ++mi)
#pragma unroll
        for (int r = 0; r < 4; ++r) {
          int x = mi * 16 + kq * 4 + r;
          float mean = acc[mi][2 * j][r] + bm;
          float sc = fmaxf(acc[mi][2 * j + 1][r] + bs, 0.11f);
          size_t zp = (size_t)((b * 130 + y + 1) * 130 + 1 + x);
          float z = bf2f(zsrc[(size_t)(f >> 3) * PSUB8 + zp * 8 + (f & 7)]);
          float is = 0.70710678118654752f / sc;
          float up = 0.5f * (1.f + erff((z - mean + 0.5f) * is));
          float lo_ = 0.5f * (1.f + erff((z - mean - 0.5f) * is));
          lik[((size_t)(b * 512 + g * 128 + f) * 128 + y) * 128 + x] = fmaxf(up - lo_, 1e-9f);
        }
    }
  }
}

// ---------- host launch ------------------------------------------------------
extern "C" void kernel_launch(void* const* d_in, const int* in_sizes, int n_in,
                              void* d_out, int out_size, void* d_ws, size_t ws_size,
                              hipStream_t stream) {
  const float* input  = (const float*)d_in[0];
  const float* cond   = (const float*)d_in[1];
  const float* lstm_w = (const float*)d_in[2];
  const float* lstm_b = (const float*)d_in[3];
  const float* w1 = (const float*)d_in[4];
  const float* b1 = (const float*)d_in[5];
  const float* w2 = (const float*)d_in[6];
  const float* b2 = (const float*)d_in[7];
  const float* w3 = (const float*)d_in[8];
  const float* b3 = (const float*)d_in[9];

  float* q   = (float*)d_out;
  float* lik = q + 33554432;

  char* ws = (char*)d_ws;
  u16* YG    = (u16*)(ws + 0);             // 4 groups x 16 8-ch planes (padded)
  u16* HAhi  = (u16*)(ws + 69222400);      // 16 planes
  u16* HBhi  = (u16*)(ws + 86528000);
  u16* T1hi  = (u16*)(ws + 103833600);     // 32 planes padded
  u16* T2hi  = (u16*)(ws + 138444800);     // 32 planes compact
  float* cbuf = (float*)(ws + 171999232);  // compact fp32 [65536][128]
  u16* WLpk = (u16*)(ws + 205553664);      // 2 x 72 x 8192 u16
  u16* W2pk = (u16*)(ws + 207912960);      // 1 x 72 x 8192
  u16* W1pk = (u16*)(ws + 209092608);      // 1 x 8 x 8192
  u16* W3pk = (u16*)(ws + 209223680);      // 1 x 8 x 8192
  float* PL = (float*)(ws + 209354752);
  float* P1 = PL + 512;
  float* P2 = P1 + 256;
  float* P3 = P2 + 256;

  // zero halos of padded activation planes (YG, HAhi, HBhi, T1hi)
  hipMemsetAsync(ws, 0, 138444800, stream);

  quant_s2d_kernel<<<131072, 256, 0, stream>>>(input, q, YG);
  s2d_cond_kernel<<<32768, 256, 0, stream>>>(cond, HAhi, cbuf);
  build_wpack<9, 0><<<4608, 256, 0, stream>>>(lstm_w, WLpk);
  build_wpack<9, 1><<<2304, 256, 0, stream>>>(w2, W2pk);
  build_wpack<1, 1><<<256, 256, 0, stream>>>(w1, W1pk);
  build_wpack<1, 2><<<256, 256, 0, stream>>>(w3, W3pk);
  make_biases<<<2, 256, 0, stream>>>(lstm_b, b1, b2, b3, PL, P1, P2, P3);

  for (int g = 0; g < 4; ++g) {
    u16* hinhi  = (g & 1) ? HBhi : HAhi;
    u16* houthi = (g & 1) ? HAhi : HBhi;
    const u16* yihi = g ? (YG + (size_t)(g - 1) * 16 * PSUB8) : hinhi;  // g=0: dead
    const u16* zg = YG + (size_t)g * 16 * PSUB8;

    // ConvLSTM 3x3: [yi, h] -> 512 gate cols, fused LSTM update
    conv_mfma<9, 512, 0><<<dim3(2, 512), 256, 0, stream>>>(
        yihi, hinhi, 130, 1, /*skiphalf=*/g ? 0 : 1,
        WLpk, PL, cbuf, houthi, PSUB8, 0, 0, nullptr, nullptr, g);
    // w1 1x1: [h, yi] -> 256, lrelu -> t1 (padded)
    conv_mfma<1, 256, 1><<<dim3(1, 512), 256, 0, stream>>>(
        houthi, yihi, 130, 1, /*skiphalf=*/g ? 0 : 2,
        W1pk, P1, nullptr, T1hi, PSUB8, 130, 1, nullptr, nullptr, g);
    // w2 3x3: t1 -> 256, lrelu -> t2 (compact)
    conv_mfma<9, 256, 1><<<dim3(1, 512), 256, 0, stream>>>(
        T1hi, T1hi + (size_t)16 * PSUB8, 130, 1, 0,
        W2pk, P2, nullptr, T2hi, TSUB8, 128, 0, nullptr, nullptr, g);
    // w3 1x1 + likelihood (compact input, stride TSUB8)
    conv_mfma<1, 256, 2><<<dim3(1, 512), 256, 0, stream>>>(
        T2hi, T2hi + (size_t)16 * TSUB8, 128, 0, 0,
        W3pk, P3, nullptr, nullptr, 0, 0, 0, zg, lik, g);
  }
}

// Round 11
// 1326.153 us; speedup vs baseline: 1.0499x; 1.0499x over previous
//
#include <hip/hip_runtime.h>
#include <math.h>

typedef unsigned short u16;
typedef __attribute__((ext_vector_type(8))) short bf16x8;
typedef __attribute__((ext_vector_type(4))) float f32x4;

#define PSUB8 540800   // elems per padded 8-ch sub-plane: 4*130*130*8
#define TSUB8 524288   // elems per compact 8-ch sub-plane: 4*128*128*8

__device__ __forceinline__ u16 f2bf(float f) {
  unsigned u = __float_as_uint(f);
  unsigned r = u + 0x7fffu + ((u >> 16) & 1u);
  return (u16)(r >> 16);
}
__device__ __forceinline__ float bf2f(u16 h) {
  return __uint_as_float(((unsigned)h) << 16);
}
__device__ __forceinline__ void gl16(const u16* g, const u16* l) {
  __builtin_amdgcn_global_load_lds(
      (const __attribute__((address_space(1))) void*)g,
      (__attribute__((address_space(3))) void*)l, 16, 0, 0);
}

// ---------- quantize + s2d into padded bf16 8-ch group planes ---------------
__global__ void quant_s2d_kernel(const float* __restrict__ inp,
                                 float* __restrict__ q,
                                 u16* __restrict__ yghi) {
  int idx = blockIdx.x * 256 + threadIdx.x;   // 33,554,432
  int ww = idx & 255;
  int hh = (idx >> 8) & 255;
  int cc = (idx >> 16) & 127;
  int b  = idx >> 23;
  float v = rintf(inp[idx]);
  q[idx] = v;
  int g = cc >> 5;
  int f = ((cc & 31) << 2) | ((hh & 1) << 1) | (ww & 1);
  int y = hh >> 1, x = ww >> 1;
  int p = (b * 130 + y + 1) * 130 + 1 + x;
  yghi[((size_t)(g * 16 + (f >> 3))) * PSUB8 + (size_t)p * 8 + (f & 7)] = f2bf(v);
}

// ---------- s2d of condition -> h0 (8-ch planes) + c0 (compact fp32) --------
__global__ void s2d_cond_kernel(const float* __restrict__ cond,
                                u16* __restrict__ hhi, float* __restrict__ c0) {
  int idx = blockIdx.x * 256 + threadIdx.x;   // 8,388,608
  int ww = idx & 255;
  int hh = (idx >> 8) & 255;
  int cc = (idx >> 16) & 31;
  int b  = idx >> 21;
  float v = cond[idx];
  int ch = (cc << 2) | ((hh & 1) << 1) | (ww & 1);
  int y = hh >> 1, x = ww >> 1;
  int p = (b * 130 + y + 1) * 130 + 1 + x;
  hhi[(size_t)(ch >> 3) * PSUB8 + (size_t)p * 8 + (ch & 7)] = f2bf(v);
  c0[((size_t)(b * 128 + y) * 128 + x) * 128 + ch] = v;
}

// ---------- weight pack: per (cb, slab) 128-col block layout ----------------
// Wpk[(cb*NSLAB+slab)*4096 + wn*2048 + ni*512 + lane*8 + jj]
// col c = cb*128 + wn*64 + ni*16 + (lane&15); k = slab*32 + (lane>>4)*8 + jj
// PERM 0: LSTM gate perm; 1: identity; 2: w3 mean/scale perm
template <int TAPS, int PERM>
__global__ void build_wpack(const float* __restrict__ w, u16* __restrict__ o) {
  int idx = blockIdx.x * 256 + threadIdx.x;
  int jj = idx & 7, lane = (idx >> 3) & 63, ni = (idx >> 9) & 3, wn = (idx >> 11) & 1;
  int rest = idx >> 12;
  const int NSLAB = TAPS * 8;
  int slab = rest % NSLAB, cb = rest / NSLAB;
  int c = cb * 128 + wn * 64 + ni * 16 + (lane & 15);
  int k = slab * 32 + ((lane >> 4) << 3) + jj;
  int tap = (TAPS == 9) ? (k >> 8) : 0;
  int ci = (TAPS == 9) ? (k & 255) : k;
  int oc;
  if (PERM == 0)      oc = ((c >> 4) & 3) * 128 + (c >> 7) * 32 + ((c >> 6) & 1) * 16 + (c & 15);
  else if (PERM == 2) oc = ((c >> 4) & 1) * 128 + (c >> 7) * 64 + ((c >> 6) & 1) * 32 + ((c >> 5) & 1) * 16 + (c & 15);
  else                oc = c;
  float v = w[((size_t)(oc * 256 + ci)) * TAPS + tap];
  o[idx] = f2bf(v);
}

__global__ void make_biases(const float* __restrict__ lb, const float* __restrict__ b1,
                            const float* __restrict__ b2, const float* __restrict__ b3,
                            float* __restrict__ pl, float* __restrict__ p1,
                            float* __restrict__ p2, float* __restrict__ p3) {
  int t = blockIdx.x * 256 + threadIdx.x;     // launch 512
  if (t < 512) {
    int gate = (t >> 4) & 3;
    int f = (t >> 7) * 32 + ((t >> 6) & 1) * 16 + (t & 15);
    pl[t] = lb[gate * 128 + f];
  }
  if (t < 256) {
    p1[t] = b1[t];
    p2[t] = b2[t];
    int m = (t >> 4) & 1;
    int f = (t >> 7) * 64 + ((t >> 6) & 1) * 32 + ((t >> 5) & 1) * 16 + (t & 15);
    p3[t] = b3[m * 128 + f];
  }
}

// ---------- MFMA conv: 128px x 128col block, 2x2 waves, 4x4 acc -------------
// R8 geometry (32KB LDS, 4 blocks/CU, vmcnt(4) counted pipeline) + R9's
// conflict-free k-major A layout. A slab in LDS: [kq(4)][px(128)][8ch] --
// staging is 8x1024B contiguous gl16 (2/wave); fragment read addr =
// kq*2048B + px*16B: each 16-lane phase reads 256B contiguous (2-way bank
// alias = free, measured 0 conflicts in R9). W per (cb,slab) contiguous 8KB,
// frag read lane*16B = 1KB contiguous, conflict-free.
// Pipeline: stage(s+1){2A+2W ops/wave} -> vmcnt(4) (stage(s) landed,
// stage(s+1) IN FLIGHT across barrier) -> s_barrier -> 16 MFMA/wave ->
// s_barrier. vmcnt(0) only on last slab.
// EPI 0: LSTM update; EPI 1: lrelu -> 8-ch planes; EPI 2: likelihood.
template <int TAPS, int NCOL, int EPI>
__global__ __launch_bounds__(256, 4)
void conv_mfma(const u16* __restrict__ a0, const u16* __restrict__ a1,
               int RS, int PAD, int skiphalf,
               const u16* __restrict__ Wpk, const float* __restrict__ biasP,
               float* __restrict__ c_io,
               u16* __restrict__ ohi, size_t OSUB, int ORS, int OPAD,
               const u16* __restrict__ zsrc, float* __restrict__ lik, int g) {
  constexpr int NSLAB = TAPS * 8;
  constexpr int NCB = NCOL / 128;
  constexpr size_t PST = (TAPS == 1 && EPI == 2) ? (size_t)TSUB8 : (size_t)PSUB8;
  __shared__ __attribute__((aligned(16))) u16 lds[16384];  // A dbuf 2x4096, W dbuf 2x4096
  const int tid = threadIdx.x;
  const int lane = tid & 63, wid = tid >> 6;
  const int wm = wid >> 1, wn = wid & 1;
  const int fl = lane & 15, kq = lane >> 4;

  // XCD swizzle: each XCD gets contiguous y-strips x all cb
  int n = blockIdx.y * NCB + blockIdx.x;
  int w_ = n >> 9, r_ = n & 511;
  int xj = r_ & 7, tt = r_ >> 3;
  const int cb = tt & (NCB - 1);
  const int YL = 64 / NCB;
  int ystrip = w_ * (8 * YL) + xj * YL + (tt / NCB);
  const int b = ystrip >> 7, y = ystrip & 127;

  const int NS = skiphalf ? NSLAB / 2 : NSLAB;
  f32x4 acc[4][4] = {};

  auto mapslab = [&](int si) -> int {
    if (!skiphalf) return si;
    int tap = si >> 2, o = si & 3;
    return tap * 8 + (skiphalf == 1 ? 4 + o : o);
  };
  auto stage = [&](int si, int buf) {   // 4 gl16 per wave (2 A + 2 W), all contiguous
    int s = mapslab(si);
    int dy = 0, dx = 0;
    if (TAPS == 9) { int tap = s >> 3; dy = tap / 3 - 1; dx = tap % 3 - 1; }
    int cc = s & 7;
    const u16* base = (cc < 4) ? a0 : a1;
    int origin = (b * RS + y + PAD) * RS + PAD + dy * RS + dx;
#pragma unroll
    for (int t = 0; t < 2; ++t) {
      int j = wid * 2 + t;              // j=0..7: kq-plane=j>>1, px-half=j&1
      const u16* src = base + (size_t)((cc & 3) * 4 + (j >> 1)) * PST
                            + (size_t)(origin + (j & 1) * 64) * 8;
      gl16(src + lane * 8, &lds[buf * 4096 + j * 512]);
    }
    const u16* wbase = Wpk + ((size_t)(cb * NSLAB + s)) * 4096;
#pragma unroll
    for (int t = 0; t < 2; ++t) {
      int j = wid * 2 + t;
      gl16(wbase + j * 512 + lane * 8, &lds[8192 + buf * 4096 + j * 512]);
    }
  };
  auto compute = [&](int buf) {
    bf16x8 Ah[4], Wf[4];
#pragma unroll
    for (int i = 0; i < 4; ++i)
      Ah[i] = *(const bf16x8*)&lds[buf * 4096 + kq * 1024 + (wm * 64 + i * 16 + fl) * 8];
#pragma unroll
    for (int i = 0; i < 4; ++i)
      Wf[i] = *(const bf16x8*)&lds[8192 + buf * 4096 + wn * 2048 + i * 512 + lane * 8];
    __builtin_amdgcn_s_setprio(1);
#pragma unroll
    for (int mi = 0; mi < 4; ++mi)
#pragma unroll
      for (int ni = 0; ni < 4; ++ni)
        acc[mi][ni] = __builtin_amdgcn_mfma_f32_16x16x32_bf16(Ah[mi], Wf[ni], acc[mi][ni], 0, 0, 0);
    __builtin_amdgcn_s_setprio(0);
  };

  stage(0, 0);
  for (int s = 0; s < NS; ++s) {
    if (s + 1 < NS) {
      stage(s + 1, (s + 1) & 1);
      asm volatile("s_waitcnt vmcnt(4)" ::: "memory");   // stage(s) landed
    } else {
      asm volatile("s_waitcnt vmcnt(0)" ::: "memory");
    }
    __builtin_amdgcn_s_barrier();       // all waves' stage(s) visible
    compute(s & 1);
    __builtin_amdgcn_s_barrier();       // reads of buf done before restage
  }

  if (EPI == 0) {
    const int f = cb * 32 + wn * 16 + fl;           // ni = gate (PERM 0)
    float bi[4];
#pragma unroll
    for (int ni = 0; ni < 4; ++ni) bi[ni] = biasP[cb * 128 + wn * 64 + ni * 16 + fl];
#pragma unroll
    for (int mi = 0; mi < 4; ++mi)
#pragma unroll
      for (int r = 0; r < 4; ++r) {
        int x = wm * 64 + mi * 16 + kq * 4 + r;
        size_t ci = ((size_t)(b * 128 + y) * 128 + x) * 128 + f;
        float ig = 1.f / (1.f + expf(-(acc[mi][0][r] + bi[0])));
        float fg = 1.f / (1.f + expf(-(acc[mi][1][r] + bi[1])));
        float og = 1.f / (1.f + expf(-(acc[mi][2][r] + bi[2])));
        float gg = tanhf(acc[mi][3][r] + bi[3]);
        float cn = fg * c_io[ci] + ig * gg;
        c_io[ci] = cn;
        float hv = og * tanhf(cn);
        size_t hx = (size_t)((b * 130 + y + 1) * 130 + 1 + x);
        ohi[(size_t)(f >> 3) * PSUB8 + hx * 8 + (f & 7)] = f2bf(hv);
      }
  } else if (EPI == 1) {
#pragma unroll
    for (int ni = 0; ni < 4; ++ni) {
      int c = cb * 128 + wn * 64 + ni * 16 + fl;    // identity perm
      float bv = biasP[c];
#pragma unroll
      for (int mi = 0; mi < 4; ++mi)
#pragma unroll
        for (int r = 0; r < 4; ++r) {
          int x = wm * 64 + mi * 16 + kq * 4 + r;
          float v = acc[mi][ni][r] + bv;
          v = (v >= 0.f) ? v : 0.01f * v;
          size_t op = (size_t)((b * ORS + y + OPAD) * ORS + OPAD + x);
          ohi[(size_t)(c >> 3) * OSUB + op * 8 + (c & 7)] = f2bf(v);
        }
    }
  } else {
#pragma unroll
    for (int j = 0; j < 2; ++j) {
      int f = cb * 64 + wn * 32 + j * 16 + fl;      // PERM 2: ni=2j mean, 2j+1 scale
      float bm = biasP[cb * 128 + wn * 64 + j * 32 + fl];
      float bs = biasP[cb * 128 + wn * 64 + j * 32 + 16 + fl];
#pragma unroll
      for (int mi = 0; mi < 4; ++mi)
#pragma unroll
        for (int r = 0; r < 4; ++r) {
          int x = wm * 64 + mi * 16 + kq * 4 + r;
          float mean = acc[mi][2 * j][r] + bm;
          float sc = fmaxf(acc[mi][2 * j + 1][r] + bs, 0.11f);
          size_t zp = (size_t)((b * 130 + y + 1) * 130 + 1 + x);
          float z = bf2f(zsrc[(size_t)(f >> 3) * PSUB8 + zp * 8 + (f & 7)]);
          float is = 0.70710678118654752f / sc;
          float up = 0.5f * (1.f + erff((z - mean + 0.5f) * is));
          float lo_ = 0.5f * (1.f + erff((z - mean - 0.5f) * is));
          lik[((size_t)(b * 512 + g * 128 + f) * 128 + y) * 128 + x] = fmaxf(up - lo_, 1e-9f);
        }
    }
  }
}

// ---------- host launch ------------------------------------------------------
extern "C" void kernel_launch(void* const* d_in, const int* in_sizes, int n_in,
                              void* d_out, int out_size, void* d_ws, size_t ws_size,
                              hipStream_t stream) {
  const float* input  = (const float*)d_in[0];
  const float* cond   = (const float*)d_in[1];
  const float* lstm_w = (const float*)d_in[2];
  const float* lstm_b = (const float*)d_in[3];
  const float* w1 = (const float*)d_in[4];
  const float* b1 = (const float*)d_in[5];
  const float* w2 = (const float*)d_in[6];
  const float* b2 = (const float*)d_in[7];
  const float* w3 = (const float*)d_in[8];
  const float* b3 = (const float*)d_in[9];

  float* q   = (float*)d_out;
  float* lik = q + 33554432;

  char* ws = (char*)d_ws;
  u16* YG    = (u16*)(ws + 0);             // 4 groups x 16 8-ch planes (padded)
  u16* HAhi  = (u16*)(ws + 69222400);      // 16 planes
  u16* HBhi  = (u16*)(ws + 86528000);
  u16* T1hi  = (u16*)(ws + 103833600);     // 32 planes padded
  u16* T2hi  = (u16*)(ws + 138444800);     // 32 planes compact
  float* cbuf = (float*)(ws + 171999232);  // compact fp32 [65536][128]
  u16* WLpk = (u16*)(ws + 205553664);      // 4 x 72 x 4096 u16
  u16* W2pk = (u16*)(ws + 207912960);      // 2 x 72 x 4096
  u16* W1pk = (u16*)(ws + 209092608);      // 2 x 8 x 4096
  u16* W3pk = (u16*)(ws + 209223680);      // 2 x 8 x 4096
  float* PL = (float*)(ws + 209354752);
  float* P1 = PL + 512;
  float* P2 = P1 + 256;
  float* P3 = P2 + 256;

  // zero halos of padded activation planes (YG, HAhi, HBhi, T1hi)
  hipMemsetAsync(ws, 0, 138444800, stream);

  quant_s2d_kernel<<<131072, 256, 0, stream>>>(input, q, YG);
  s2d_cond_kernel<<<32768, 256, 0, stream>>>(cond, HAhi, cbuf);
  build_wpack<9, 0><<<4608, 256, 0, stream>>>(lstm_w, WLpk);
  build_wpack<9, 1><<<2304, 256, 0, stream>>>(w2, W2pk);
  build_wpack<1, 1><<<256, 256, 0, stream>>>(w1, W1pk);
  build_wpack<1, 2><<<256, 256, 0, stream>>>(w3, W3pk);
  make_biases<<<2, 256, 0, stream>>>(lstm_b, b1, b2, b3, PL, P1, P2, P3);

  for (int g = 0; g < 4; ++g) {
    u16* hinhi  = (g & 1) ? HBhi : HAhi;
    u16* houthi = (g & 1) ? HAhi : HBhi;
    const u16* yihi = g ? (YG + (size_t)(g - 1) * 16 * PSUB8) : hinhi;  // g=0: dead
    const u16* zg = YG + (size_t)g * 16 * PSUB8;

    // ConvLSTM 3x3: [yi, h] -> 512 gate cols, fused LSTM update
    conv_mfma<9, 512, 0><<<dim3(4, 512), 256, 0, stream>>>(
        yihi, hinhi, 130, 1, /*skiphalf=*/g ? 0 : 1,
        WLpk, PL, cbuf, houthi, PSUB8, 0, 0, nullptr, nullptr, g);
    // w1 1x1: [h, yi] -> 256, lrelu -> t1 (padded)
    conv_mfma<1, 256, 1><<<dim3(2, 512), 256, 0, stream>>>(
        houthi, yihi, 130, 1, /*skiphalf=*/g ? 0 : 2,
        W1pk, P1, nullptr, T1hi, PSUB8, 130, 1, nullptr, nullptr, g);
    // w2 3x3: t1 -> 256, lrelu -> t2 (compact)
    conv_mfma<9, 256, 1><<<dim3(2, 512), 256, 0, stream>>>(
        T1hi, T1hi + (size_t)16 * PSUB8, 130, 1, 0,
        W2pk, P2, nullptr, T2hi, TSUB8, 128, 0, nullptr, nullptr, g);
    // w3 1x1 + likelihood (compact input, stride TSUB8)
    conv_mfma<1, 256, 2><<<dim3(2, 512), 256, 0, stream>>>(
        T2hi, T2hi + (size_t)16 * TSUB8, 128, 0, 0,
        W3pk, P3, nullptr, nullptr, 0, 0, 0, zg, lik, g);
  }
}

// Round 12
// 1178.535 us; speedup vs baseline: 1.1814x; 1.1253x over previous
//
#include <hip/hip_runtime.h>
#include <math.h>

typedef unsigned short u16;
typedef __attribute__((ext_vector_type(8))) short bf16x8;
typedef __attribute__((ext_vector_type(4))) float f32x4;

#define PSUB8 540800   // elems per padded 8-ch sub-plane: 4*130*130*8
#define TSUB8 524288   // elems per compact 8-ch sub-plane: 4*128*128*8

__device__ __forceinline__ u16 f2bf(float f) {
  unsigned u = __float_as_uint(f);
  unsigned r = u + 0x7fffu + ((u >> 16) & 1u);
  return (u16)(r >> 16);
}
__device__ __forceinline__ float bf2f(u16 h) {
  return __uint_as_float(((unsigned)h) << 16);
}
__device__ __forceinline__ void gl16(const u16* g, const u16* l) {
  __builtin_amdgcn_global_load_lds(
      (const __attribute__((address_space(1))) void*)g,
      (__attribute__((address_space(3))) void*)l, 16, 0, 0);
}
__device__ __forceinline__ float sigm_f(float x) {
  return __builtin_amdgcn_rcpf(1.f + __expf(-x));
}
__device__ __forceinline__ float tanh_f(float x) {
  float xc = fminf(fmaxf(x, -20.f), 20.f);
  float e = __expf(2.f * xc);
  return (e - 1.f) * __builtin_amdgcn_rcpf(e + 1.f);
}

// ---------- quantize + s2d into padded bf16 8-ch group planes ---------------
__global__ void quant_s2d_kernel(const float* __restrict__ inp,
                                 float* __restrict__ q,
                                 u16* __restrict__ yghi) {
  int idx = blockIdx.x * 256 + threadIdx.x;   // 33,554,432
  int ww = idx & 255;
  int hh = (idx >> 8) & 255;
  int cc = (idx >> 16) & 127;
  int b  = idx >> 23;
  float v = rintf(inp[idx]);
  q[idx] = v;
  int g = cc >> 5;
  int f = ((cc & 31) << 2) | ((hh & 1) << 1) | (ww & 1);
  int y = hh >> 1, x = ww >> 1;
  int p = (b * 130 + y + 1) * 130 + 1 + x;
  yghi[((size_t)(g * 16 + (f >> 3))) * PSUB8 + (size_t)p * 8 + (f & 7)] = f2bf(v);
}

// ---------- s2d of condition -> h0 (8-ch planes) + c0 (compact fp32) --------
__global__ void s2d_cond_kernel(const float* __restrict__ cond,
                                u16* __restrict__ hhi, float* __restrict__ c0) {
  int idx = blockIdx.x * 256 + threadIdx.x;   // 8,388,608
  int ww = idx & 255;
  int hh = (idx >> 8) & 255;
  int cc = (idx >> 16) & 31;
  int b  = idx >> 21;
  float v = cond[idx];
  int ch = (cc << 2) | ((hh & 1) << 1) | (ww & 1);
  int y = hh >> 1, x = ww >> 1;
  int p = (b * 130 + y + 1) * 130 + 1 + x;
  hhi[(size_t)(ch >> 3) * PSUB8 + (size_t)p * 8 + (ch & 7)] = f2bf(v);
  c0[((size_t)(b * 128 + y) * 128 + x) * 128 + ch] = v;
}

// ---------- zero only the halos of the 128 contiguous padded planes --------
__global__ void zero_halos(u16* __restrict__ base) {
  int e = blockIdx.x * 256 + threadIdx.x;     // 0..4351, need 516*8=4128
  if (e >= 516 * 8) return;
  int pb = blockIdx.y;                        // plane*4 + b, 512 total
  int px = e >> 3, ch = e & 7;
  int y, x;
  if (px < 130)      { y = 0;            x = px; }
  else if (px < 260) { y = 129;          x = px - 130; }
  else if (px < 388) { y = px - 260 + 1; x = 0; }
  else               { y = px - 388 + 1; x = 129; }
  int plane = pb >> 2, b = pb & 3;
  base[(size_t)plane * PSUB8 + (size_t)((b * 130 + y) * 130 + x) * 8 + ch] = 0;
}

// ---------- weight pack: per (cb, slab) 128-col block layout ----------------
// Wpk[(cb*NSLAB+slab)*4096 + wn*2048 + ni*512 + lane*8 + jj]
// col c = cb*128 + wn*64 + ni*16 + (lane&15); k = slab*32 + (lane>>4)*8 + jj
// PERM 0: LSTM gate perm; 1: identity; 2: w3 mean/scale perm
template <int TAPS, int PERM>
__global__ void build_wpack(const float* __restrict__ w, u16* __restrict__ o) {
  int idx = blockIdx.x * 256 + threadIdx.x;
  int jj = idx & 7, lane = (idx >> 3) & 63, ni = (idx >> 9) & 3, wn = (idx >> 11) & 1;
  int rest = idx >> 12;
  const int NSLAB = TAPS * 8;
  int slab = rest % NSLAB, cb = rest / NSLAB;
  int c = cb * 128 + wn * 64 + ni * 16 + (lane & 15);
  int k = slab * 32 + ((lane >> 4) << 3) + jj;
  int tap = (TAPS == 9) ? (k >> 8) : 0;
  int ci = (TAPS == 9) ? (k & 255) : k;
  int oc;
  if (PERM == 0)      oc = ((c >> 4) & 3) * 128 + (c >> 7) * 32 + ((c >> 6) & 1) * 16 + (c & 15);
  else if (PERM == 2) oc = ((c >> 4) & 1) * 128 + (c >> 7) * 64 + ((c >> 6) & 1) * 32 + ((c >> 5) & 1) * 16 + (c & 15);
  else                oc = c;
  float v = w[((size_t)(oc * 256 + ci)) * TAPS + tap];
  o[idx] = f2bf(v);
}

__global__ void make_biases(const float* __restrict__ lb, const float* __restrict__ b1,
                            const float* __restrict__ b2, const float* __restrict__ b3,
                            float* __restrict__ pl, float* __restrict__ p1,
                            float* __restrict__ p2, float* __restrict__ p3) {
  int t = blockIdx.x * 256 + threadIdx.x;     // launch 512
  if (t < 512) {
    int gate = (t >> 4) & 3;
    int f = (t >> 7) * 32 + ((t >> 6) & 1) * 16 + (t & 15);
    pl[t] = lb[gate * 128 + f];
  }
  if (t < 256) {
    p1[t] = b1[t];
    p2[t] = b2[t];
    int m = (t >> 4) & 1;
    int f = (t >> 7) * 64 + ((t >> 6) & 1) * 32 + ((t >> 5) & 1) * 16 + (t & 15);
    p3[t] = b3[m * 128 + f];
  }
}

// ---------- MFMA conv: R11 structure, fully constant-folded K-loop ----------
// SKIP/RS/PAD/PST are compile-time; the NS-slab loop is #pragma unroll'd so
// every staging address reduces to uniform-base + (lane*8 + literal), every
// LDS offset to base + 16-bit immediate. Pipeline & layout identical to R11:
// stage(s+1){2A+2W gl16} -> vmcnt(4) -> s_barrier -> 16 MFMA -> s_barrier.
// EPI 0: LSTM update; EPI 1: lrelu -> 8-ch planes; EPI 2: likelihood.
template <int TAPS, int NCOL, int EPI, int SKIP>
__global__ __launch_bounds__(256, 4)
void conv_mfma(const u16* __restrict__ a0, const u16* __restrict__ a1,
               const u16* __restrict__ Wpk, const float* __restrict__ biasP,
               float* __restrict__ c_io,
               u16* __restrict__ ohi, size_t OSUB, int ORS, int OPAD,
               const u16* __restrict__ zsrc, float* __restrict__ lik, int g) {
  constexpr int NSLAB = TAPS * 8;
  constexpr int NS = SKIP ? NSLAB / 2 : NSLAB;
  constexpr int NCB = NCOL / 128;
  constexpr bool COMPACT = (EPI == 2);
  constexpr int RS = COMPACT ? 128 : 130;
  constexpr int PAD = COMPACT ? 0 : 1;
  constexpr size_t PST = COMPACT ? (size_t)TSUB8 : (size_t)PSUB8;
  __shared__ __attribute__((aligned(16))) u16 lds[16384];  // A dbuf 2x4096, W dbuf 2x4096
  const int tid = threadIdx.x;
  const int lane = tid & 63, wid = tid >> 6;
  const int wm = wid >> 1, wn = wid & 1;
  const int fl = lane & 15, kq = lane >> 4;

  // XCD swizzle: each XCD gets contiguous y-strips x all cb
  int n = blockIdx.y * NCB + blockIdx.x;
  int w_ = n >> 9, r_ = n & 511;
  int xj = r_ & 7, tt = r_ >> 3;
  const int cb = tt & (NCB - 1);
  const int YL = 64 / NCB;
  int ystrip = w_ * (8 * YL) + xj * YL + (tt / NCB);
  const int b = ystrip >> 7, y = ystrip & 127;

  f32x4 acc[4][4] = {};

  const int origin0 = (b * RS + y + PAD) * RS + PAD;
  // per-wave uniform-ish bases (wid*PST folds the j>>1 plane select)
  const u16* a0w = a0 + (size_t)origin0 * 8 + (size_t)wid * PST;
  const u16* a1w = a1 + (size_t)origin0 * 8 + (size_t)wid * PST;
  const u16* Ww  = Wpk + (size_t)cb * NSLAB * 4096 + (size_t)wid * 1024 + (size_t)lane * 8;
  u16* ldsA = &lds[wid * 1024];
  u16* ldsW = &lds[8192 + wid * 1024];

  auto stage = [&](int si, int buf) {
    int ms;
    if (SKIP == 0) ms = si;
    else {
      int tp = si >> 2, o = si & 3;
      ms = tp * 8 + (SKIP == 1 ? 4 + o : o);
    }
    int cc = ms & 7;
    int tap = ms >> 3;
    int dy = (TAPS == 9) ? tap / 3 - 1 : 0;
    int dx = (TAPS == 9) ? tap % 3 - 1 : 0;
    const u16* aw = (cc < 4) ? a0w : a1w;
    long abase = (long)(cc & 3) * 4 * (long)PST + (long)(dy * RS + dx) * 8;
#pragma unroll
    for (int t = 0; t < 2; ++t)
      gl16(aw + abase + t * 512 + lane * 8, ldsA + buf * 4096 + t * 512);
#pragma unroll
    for (int t = 0; t < 2; ++t)
      gl16(Ww + (long)ms * 4096 + t * 512, ldsW + buf * 4096 + t * 512);
  };
  auto compute = [&](int buf) {
    bf16x8 Ah[4], Wf[4];
#pragma unroll
    for (int i = 0; i < 4; ++i)
      Ah[i] = *(const bf16x8*)&lds[buf * 4096 + kq * 1024 + (wm * 64 + i * 16 + fl) * 8];
#pragma unroll
    for (int i = 0; i < 4; ++i)
      Wf[i] = *(const bf16x8*)&lds[8192 + buf * 4096 + wn * 2048 + i * 512 + lane * 8];
    __builtin_amdgcn_s_setprio(1);
#pragma unroll
    for (int mi = 0; mi < 4; ++mi)
#pragma unroll
      for (int ni = 0; ni < 4; ++ni)
        acc[mi][ni] = __builtin_amdgcn_mfma_f32_16x16x32_bf16(Ah[mi], Wf[ni], acc[mi][ni], 0, 0, 0);
    __builtin_amdgcn_s_setprio(0);
  };

  stage(0, 0);
#pragma unroll
  for (int s = 0; s < NS; ++s) {
    if (s + 1 < NS) {
      stage(s + 1, (s + 1) & 1);
      asm volatile("s_waitcnt vmcnt(4)" ::: "memory");   // stage(s) landed
    } else {
      asm volatile("s_waitcnt vmcnt(0)" ::: "memory");
    }
    __builtin_amdgcn_s_barrier();       // all waves' stage(s) visible
    compute(s & 1);
    __builtin_amdgcn_s_barrier();       // reads of buf done before restage
  }

  if (EPI == 0) {
    const int f = cb * 32 + wn * 16 + fl;           // ni = gate (PERM 0)
    float bi[4];
#pragma unroll
    for (int ni = 0; ni < 4; ++ni) bi[ni] = biasP[cb * 128 + wn * 64 + ni * 16 + fl];
#pragma unroll
    for (int mi = 0; mi < 4; ++mi)
#pragma unroll
      for (int r = 0; r < 4; ++r) {
        int x = wm * 64 + mi * 16 + kq * 4 + r;
        size_t ci = ((size_t)(b * 128 + y) * 128 + x) * 128 + f;
        float ig = sigm_f(acc[mi][0][r] + bi[0]);
        float fg = sigm_f(acc[mi][1][r] + bi[1]);
        float og = sigm_f(acc[mi][2][r] + bi[2]);
        float gg = tanh_f(acc[mi][3][r] + bi[3]);
        float cn = fg * c_io[ci] + ig * gg;
        c_io[ci] = cn;
        float hv = og * tanh_f(cn);
        size_t hx = (size_t)((b * 130 + y + 1) * 130 + 1 + x);
        ohi[(size_t)(f >> 3) * PSUB8 + hx * 8 + (f & 7)] = f2bf(hv);
      }
  } else if (EPI == 1) {
#pragma unroll
    for (int ni = 0; ni < 4; ++ni) {
      int c = cb * 128 + wn * 64 + ni * 16 + fl;    // identity perm
      float bv = biasP[c];
#pragma unroll
      for (int mi = 0; mi < 4; ++mi)
#pragma unroll
        for (int r = 0; r < 4; ++r) {
          int x = wm * 64 + mi * 16 + kq * 4 + r;
          float v = acc[mi][ni][r] + bv;
          v = (v >= 0.f) ? v : 0.01f * v;
          size_t op = (size_t)((b * ORS + y + OPAD) * ORS + OPAD + x);
          ohi[(size_t)(c >> 3) * OSUB + op * 8 + (c & 7)] = f2bf(v);
        }
    }
  } else {
#pragma unroll
    for (int j = 0; j < 2; ++j) {
      int f = cb * 64 + wn * 32 + j * 16 + fl;      // PERM 2: ni=2j mean, 2j+1 scale
      float bm = biasP[cb * 128 + wn * 64 + j * 32 + fl];
      float bs = biasP[cb * 128 + wn * 64 + j * 32 + 16 + fl];
#pragma unroll
      for (int mi = 0; mi < 4; ++mi)
#pragma unroll
        for (int r = 0; r < 4; ++r) {
          int x = wm * 64 + mi * 16 + kq * 4 + r;
          float mean = acc[mi][2 * j][r] + bm;
          float sc = fmaxf(acc[mi][2 * j + 1][r] + bs, 0.11f);
          size_t zp = (size_t)((b * 130 + y + 1) * 130 + 1 + x);
          float z = bf2f(zsrc[(size_t)(f >> 3) * PSUB8 + zp * 8 + (f & 7)]);
          float is = 0.70710678118654752f / sc;
          float up = 0.5f * (1.f + erff((z - mean + 0.5f) * is));
          float lo_ = 0.5f * (1.f + erff((z - mean - 0.5f) * is));
          lik[((size_t)(b * 512 + g * 128 + f) * 128 + y) * 128 + x] = fmaxf(up - lo_, 1e-9f);
        }
    }
  }
}

// ---------- host launch ------------------------------------------------------
extern "C" void kernel_launch(void* const* d_in, const int* in_sizes, int n_in,
                              void* d_out, int out_size, void* d_ws, size_t ws_size,
                              hipStream_t stream) {
  const float* input  = (const float*)d_in[0];
  const float* cond   = (const float*)d_in[1];
  const float* lstm_w = (const float*)d_in[2];
  const float* lstm_b = (const float*)d_in[3];
  const float* w1 = (const float*)d_in[4];
  const float* b1 = (const float*)d_in[5];
  const float* w2 = (const float*)d_in[6];
  const float* b2 = (const float*)d_in[7];
  const float* w3 = (const float*)d_in[8];
  const float* b3 = (const float*)d_in[9];

  float* q   = (float*)d_out;
  float* lik = q + 33554432;

  char* ws = (char*)d_ws;
  u16* YG    = (u16*)(ws + 0);             // 4 groups x 16 8-ch planes (padded)
  u16* HAhi  = (u16*)(ws + 69222400);      // 16 planes
  u16* HBhi  = (u16*)(ws + 86528000);
  u16* T1hi  = (u16*)(ws + 103833600);     // 32 planes padded
  u16* T2hi  = (u16*)(ws + 138444800);     // 32 planes compact
  float* cbuf = (float*)(ws + 171999232);  // compact fp32 [65536][128]
  u16* WLpk = (u16*)(ws + 205553664);      // 4 x 72 x 4096 u16
  u16* W2pk = (u16*)(ws + 207912960);      // 2 x 72 x 4096
  u16* W1pk = (u16*)(ws + 209092608);      // 2 x 8 x 4096
  u16* W3pk = (u16*)(ws + 209223680);      // 2 x 8 x 4096
  float* PL = (float*)(ws + 209354752);
  float* P1 = PL + 512;
  float* P2 = P1 + 256;
  float* P3 = P2 + 256;

  // zero halos only (interiors rewritten every call; 4 MB vs 138 MB memset)
  zero_halos<<<dim3(17, 512), 256, 0, stream>>>((u16*)ws);

  quant_s2d_kernel<<<131072, 256, 0, stream>>>(input, q, YG);
  s2d_cond_kernel<<<32768, 256, 0, stream>>>(cond, HAhi, cbuf);
  build_wpack<9, 0><<<4608, 256, 0, stream>>>(lstm_w, WLpk);
  build_wpack<9, 1><<<2304, 256, 0, stream>>>(w2, W2pk);
  build_wpack<1, 1><<<256, 256, 0, stream>>>(w1, W1pk);
  build_wpack<1, 2><<<256, 256, 0, stream>>>(w3, W3pk);
  make_biases<<<2, 256, 0, stream>>>(lstm_b, b1, b2, b3, PL, P1, P2, P3);

  for (int g = 0; g < 4; ++g) {
    u16* hinhi  = (g & 1) ? HBhi : HAhi;
    u16* houthi = (g & 1) ? HAhi : HBhi;
    const u16* yihi = g ? (YG + (size_t)(g - 1) * 16 * PSUB8) : hinhi;  // g=0: dead
    const u16* zg = YG + (size_t)g * 16 * PSUB8;

    if (g == 0) {
      // ConvLSTM 3x3 (skip yi half), fused LSTM update
      conv_mfma<9, 512, 0, 1><<<dim3(4, 512), 256, 0, stream>>>(
          hinhi, hinhi, WLpk, PL, cbuf, houthi, PSUB8, 0, 0, nullptr, nullptr, g);
      // w1 1x1 (skip yi half), lrelu -> t1 (padded)
      conv_mfma<1, 256, 1, 2><<<dim3(2, 512), 256, 0, stream>>>(
          houthi, houthi, W1pk, P1, nullptr, T1hi, PSUB8, 130, 1, nullptr, nullptr, g);
    } else {
      conv_mfma<9, 512, 0, 0><<<dim3(4, 512), 256, 0, stream>>>(
          yihi, hinhi, WLpk, PL, cbuf, houthi, PSUB8, 0, 0, nullptr, nullptr, g);
      conv_mfma<1, 256, 1, 0><<<dim3(2, 512), 256, 0, stream>>>(
          houthi, yihi, W1pk, P1, nullptr, T1hi, PSUB8, 130, 1, nullptr, nullptr, g);
    }
    // w2 3x3: t1 -> 256, lrelu -> t2 (compact)
    conv_mfma<9, 256, 1, 0><<<dim3(2, 512), 256, 0, stream>>>(
        T1hi, T1hi + (size_t)16 * PSUB8, W2pk, P2, nullptr, T2hi, TSUB8, 128, 0,
        nullptr, nullptr, g);
    // w3 1x1 + likelihood (compact input)
    conv_mfma<1, 256, 2, 0><<<dim3(2, 512), 256, 0, stream>>>(
        T2hi, T2hi + (size_t)16 * TSUB8, W3pk, P3, nullptr, nullptr, 0, 0, 0,
        zg, lik, g);
  }
}